// Round 4
// baseline (154.225 us; speedup 1.0000x reference)
//
#include <hip/hip_runtime.h>
#include <math.h>

#define N 8192
#define D 128
#define MARGIN 0.2f
#define PD_EPS 1e-6f

#define NLAB 16
#define NSUB 32
#define MAXPADL (N + NLAB * 64)      // 9216 padded label-sorted rows
#define MAXPADS (N + NSUB * 64)      // 10240 padded subject-sorted rows
#define MAXWL 144                    // sum ceil(cntL/64) <= 128+16
#define MAXWS 160                    // sum ceil(cntS/64) <= 128+32
#define MAXW  (MAXWL + MAXWS)        // 304 mining waves
#define MINEBLOCKS ((MAXW + 3) / 4)  // 76 blocks x 4 waves

typedef __attribute__((ext_vector_type(8))) short bf16x8;  // 8 bf16 = 4 VGPRs
typedef __attribute__((ext_vector_type(4))) float f32x4;

__device__ __forceinline__ unsigned short f2bf(float f) {
    unsigned u = __float_as_uint(f);
    u += 0x7FFFu + ((u >> 16) & 1u);   // round-to-nearest-even
    return (unsigned short)(u >> 16);
}
__device__ __forceinline__ unsigned umn(unsigned a, unsigned b) { return a < b ? a : b; }
__device__ __forceinline__ unsigned umx(unsigned a, unsigned b) { return a > b ? a : b; }

// ---------------- kernel 0: counting-sort rows into label & subject buckets --
// Single block. Produces, for each padded bucket space X in {L(abel),S(ubject)}:
//   metaX[k]  = 9-bit meta of permuted row k, or 1024 for pad slots
//   permX[k]  = original row index, or N for pad slots
//   posX[i]   = permuted position of original row i (for k_normalize scatter)
// plus per-wave mining tables wvA (anchor base), wvJ (j base), wvT (tile count).
__global__ __launch_bounds__(256) void k_buckets(const int* __restrict__ labels,
                                                 const int* __restrict__ subjects,
                                                 int* __restrict__ metaL, int* __restrict__ permL,
                                                 int* __restrict__ posL,
                                                 int* __restrict__ metaS, int* __restrict__ permS,
                                                 int* __restrict__ posS,
                                                 int* __restrict__ wvA, int* __restrict__ wvJ,
                                                 int* __restrict__ wvT) {
    __shared__ int cL[NLAB], cS[NSUB], rL[NLAB], rS[NSUB], pbL[NLAB + 1], pbS[NSUB + 1];
    const int t = threadIdx.x;
    if (t < NLAB) { cL[t] = 0; rL[t] = 0; }
    if (t < NSUB) { cS[t] = 0; rS[t] = 0; }
    __syncthreads();
    for (int i = t; i < N; i += 256) {
        atomicAdd(&cL[labels[i]], 1);
        atomicAdd(&cS[subjects[i]], 1);
    }
    __syncthreads();
    if (t == 0) {
        int a = 0;
        for (int b = 0; b < NLAB; ++b) { pbL[b] = a; a += (cL[b] + 63) & ~63; }
        pbL[NLAB] = a;
        a = 0;
        for (int b = 0; b < NSUB; ++b) { pbS[b] = a; a += (cS[b] + 63) & ~63; }
        pbS[NSUB] = a;
    }
    __syncthreads();
    // init everything to pad values, then scatter the real rows over it
    for (int k = t; k < MAXPADL; k += 256) { metaL[k] = 1024; permL[k] = N; }
    for (int k = t; k < MAXPADS; k += 256) { metaS[k] = 1024; permS[k] = N; }
    __syncthreads();
    for (int i = t; i < N; i += 256) {
        int lab = labels[i], sub = subjects[i], me = lab * 32 + sub;
        int kl = pbL[lab] + atomicAdd(&rL[lab], 1);
        metaL[kl] = me; permL[kl] = i; posL[i] = kl;
        int ks = pbS[sub] + atomicAdd(&rS[sub], 1);
        metaS[ks] = me; permS[ks] = i; posS[i] = ks;
    }
    if (t == 0) {   // wave tables (depend only on counts)
        int w = 0;
        for (int b = 0; b < NLAB; ++b) {
            int nt = (cL[b] + 63) >> 6;
            for (int q = 0; q < nt; ++q) { wvA[w] = pbL[b] + q * 64; wvJ[w] = pbL[b]; wvT[w] = nt; ++w; }
        }
        for (; w < MAXWL; ++w) { wvA[w] = 0; wvJ[w] = 0; wvT[w] = 0; }
        w = MAXWL;
        for (int b = 0; b < NSUB; ++b) {
            int nt = (cS[b] + 63) >> 6;
            for (int q = 0; q < nt; ++q) { wvA[w] = pbS[b] + q * 64; wvJ[w] = pbS[b]; wvT[w] = nt; ++w; }
        }
        for (; w < MAXW; ++w) { wvA[w] = 0; wvJ[w] = 0; wvT[w] = 0; }
    }
}

// ---------------- kernel 1: normalize -> bf16 rows scattered into buckets ----
__global__ __launch_bounds__(256) void k_normalize(const float* __restrict__ z,
                                                   const int* __restrict__ posL,
                                                   const int* __restrict__ posS,
                                                   unsigned short* __restrict__ znbL,
                                                   unsigned short* __restrict__ znbS,
                                                   float* __restrict__ invn) {
    int row  = blockIdx.x * 4 + (threadIdx.x >> 6);
    int lane = threadIdx.x & 63;
    float2 v = ((const float2*)(z + (size_t)row * D))[lane];
    float ss = v.x * v.x + v.y * v.y;
    #pragma unroll
    for (int m = 1; m < 64; m <<= 1) ss += __shfl_xor(ss, m, 64);
    float norm = fmaxf(sqrtf(ss), 1e-12f);
    ushort2 b; b.x = f2bf(v.x / norm); b.y = f2bf(v.y / norm);
    int kl = posL[row], ks = posS[row];
    ((ushort2*)(znbL + (size_t)kl * D))[lane] = b;
    ((ushort2*)(znbS + (size_t)ks * D))[lane] = b;
    if (lane == 0) invn[row] = 1.0f / norm;
}

// ---------------- kernel 2: bucketed MFMA mining -----------------------------
// Wave w < MAXWL: pos-mining inside one label bucket (cond: subject differs,
// x=(mi^mj) in [1,31]). Wave w >= MAXWL: neg-mining inside one subject bucket
// (cond: label differs, x in {32,...,480}). Pad slots carry meta=1024 so the
// single unsigned compare (x-1u)<thr excludes pads AND the diagonal for free.
// Keys: (bits(dot+2) & ~8191) | orig_j, XOR'd with `inv` so min-reduce serves
// both min (pos, inv=0) and max (neg, inv=~0). 10.7x fewer dots than full NxN.
__global__ __launch_bounds__(256) void k_mine(const unsigned short* __restrict__ znbL,
                                              const unsigned short* __restrict__ znbS,
                                              const int* __restrict__ metaL, const int* __restrict__ permL,
                                              const int* __restrict__ metaS, const int* __restrict__ permS,
                                              const int* __restrict__ wvA, const int* __restrict__ wvJ,
                                              const int* __restrict__ wvT,
                                              unsigned* __restrict__ posk, unsigned* __restrict__ negk) {
    const int wave = threadIdx.x >> 6;
    const int lane = threadIdx.x & 63;
    const int w    = blockIdx.x * 4 + wave;
    const int nt   = wvT[w];
    if (nt == 0) return;                          // unused slot (wave-uniform)
    const bool isPos = (w < MAXWL);
    const unsigned short* zb = isPos ? znbL : znbS;
    const int* mt = isPos ? metaL : metaS;
    const int* pm = isPos ? permL : permS;
    const unsigned thr = isPos ? 31u : 1023u;
    const unsigned inv = isPos ? 0u : 0xFFFFFFFFu;
    const int ab = wvA[w];                        // anchor base (padded space)
    const int jb = wvJ[w];                        // bucket j base
    const int m    = lane & 15;
    const int quad = lane >> 4;

    // persistent A fragments (round-0 proven layout): row ab+u*16+m, k=s*32+quad*8
    bf16x8 afrag[4][4];
    #pragma unroll
    for (int u = 0; u < 4; ++u)
        #pragma unroll
        for (int s = 0; s < 4; ++s)
            afrag[u][s] = *(const bf16x8*)(zb + (size_t)(ab + u * 16 + m) * D + s * 32 + quad * 8);

    int mi[16];
    #pragma unroll
    for (int u = 0; u < 4; ++u)
        #pragma unroll
        for (int r = 0; r < 4; ++r)
            mi[u * 4 + r] = mt[ab + u * 16 + quad * 4 + r];

    unsigned best[16];
    #pragma unroll
    for (int s = 0; s < 16; ++s) best[s] = 0xFFFFFFFFu;

    for (int t = 0; t < nt; ++t) {
        const int jt = jb + t * 64;
        int mjv[4], jov[4];
        #pragma unroll
        for (int v = 0; v < 4; ++v) {
            int jr = jt + v * 16 + m;
            mjv[v] = mt[jr];
            jov[v] = pm[jr];                      // original j index for the key
        }

        f32x4 acc[4][4];
        #pragma unroll
        for (int u = 0; u < 4; ++u)
            #pragma unroll
            for (int v = 0; v < 4; ++v)
                acc[u][v] = (f32x4){0.f, 0.f, 0.f, 0.f};

        #pragma unroll
        for (int s = 0; s < 4; ++s) {
            bf16x8 bf[4];
            #pragma unroll
            for (int v = 0; v < 4; ++v)
                bf[v] = *(const bf16x8*)(zb + (size_t)(jt + v * 16 + m) * D + s * 32 + quad * 8);
            #pragma unroll
            for (int u = 0; u < 4; ++u)
                #pragma unroll
                for (int v = 0; v < 4; ++v)
                    acc[u][v] = __builtin_amdgcn_mfma_f32_16x16x32_bf16(afrag[u][s], bf[v], acc[u][v], 0, 0, 0);
        }

        // epilogue: C/D layout col=lane&15 (j), row=quad*4+r (anchor) — m89-verified
        #pragma unroll
        for (int v = 0; v < 4; ++v) {
            #pragma unroll
            for (int u = 0; u < 4; ++u)
                #pragma unroll
                for (int r = 0; r < 4; ++r) {
                    float dot = acc[u][v][r];
                    unsigned key = (((__float_as_uint(dot + 2.0f)) & 0xFFFFE000u) | (unsigned)jov[v]) ^ inv;
                    unsigned x = (unsigned)(mi[u * 4 + r] ^ mjv[v]);
                    bool c = (x - 1u) < thr;      // one cmp: excludes diagonal + pads
                    best[u * 4 + r] = umn(best[u * 4 + r], c ? key : 0xFFFFFFFFu);
                }
        }
    }

    // merge across the 16 lanes (different j) sharing each (quad, slot)
    #pragma unroll
    for (int mm = 1; mm < 16; mm <<= 1)
        #pragma unroll
        for (int s = 0; s < 16; ++s)
            best[s] = umn(best[s], (unsigned)__shfl_xor((int)best[s], mm, 64));

    if (m == 0) {
        unsigned* dst = isPos ? posk : negk;
        #pragma unroll
        for (int u = 0; u < 4; ++u)
            #pragma unroll
            for (int r = 0; r < 4; ++r) {
                int orig = pm[ab + u * 16 + quad * 4 + r];
                if (orig < N) dst[orig] = best[u * 4 + r] ^ inv;  // pads skipped
            }
    }
}

// ---------------- kernel 3: fp32 hinge on mined indices ----------------------
__global__ __launch_bounds__(256) void k_final(const float* __restrict__ z,
                                               const float* __restrict__ invn,
                                               const unsigned* __restrict__ posk,
                                               const unsigned* __restrict__ negk,
                                               float* __restrict__ per, float* __restrict__ vld) {
    int row  = blockIdx.x * 4 + (threadIdx.x >> 6);
    int lane = threadIdx.x & 63;
    unsigned mp = posk[row];   // min-key or ~0 sentinel
    unsigned mn = negk[row];   // max-key or 0 sentinel
    bool valid = (mp != 0xFFFFFFFFu) && (mn != 0u);
    int pi = valid ? (int)(mp & 8191u) : 0;
    int ni = valid ? (int)(mn & 8191u) : 0;
    float ia = invn[row], ip = invn[pi], iq = invn[ni];
    float2 a = ((const float2*)(z + (size_t)row * D))[lane];
    float2 p = ((const float2*)(z + (size_t)pi  * D))[lane];
    float2 q = ((const float2*)(z + (size_t)ni  * D))[lane];
    float dx = a.x * ia - p.x * ip + PD_EPS, dy = a.y * ia - p.y * ip + PD_EPS;
    float sap = dx * dx + dy * dy;
    dx = a.x * ia - q.x * iq + PD_EPS; dy = a.y * ia - q.y * iq + PD_EPS;
    float san = dx * dx + dy * dy;
    #pragma unroll
    for (int m = 1; m < 64; m <<= 1) {
        sap += __shfl_xor(sap, m, 64);
        san += __shfl_xor(san, m, 64);
    }
    if (lane == 0) {
        float l = fmaxf(sqrtf(sap) - sqrtf(san) + MARGIN, 0.0f);
        per[row] = valid ? l : 0.0f;
        vld[row] = valid ? 1.0f : 0.0f;
    }
}

// ---------------- kernel 4: deterministic final reduce -----------------------
__global__ __launch_bounds__(256) void k_reduce(const float* __restrict__ per,
                                                const float* __restrict__ vld,
                                                float* __restrict__ out) {
    __shared__ float s1[256], s2[256];
    int t = threadIdx.x;
    float a = 0.f, b = 0.f;
    for (int i = t; i < N; i += 256) { a += per[i]; b += vld[i]; }
    s1[t] = a; s2[t] = b;
    __syncthreads();
    for (int w = 128; w > 0; w >>= 1) {
        if (t < w) { s1[t] += s1[t + w]; s2[t] += s2[t + w]; }
        __syncthreads();
    }
    if (t == 0) {
        float cnt = s2[0];
        out[0] = (cnt > 0.f) ? s1[0] / fmaxf(cnt, 1.f) : 0.f;
    }
}

extern "C" void kernel_launch(void* const* d_in, const int* in_sizes, int n_in,
                              void* d_out, int out_size, void* d_ws, size_t ws_size,
                              hipStream_t stream) {
    const float* z        = (const float*)d_in[0];
    const int*   labels   = (const int*)d_in[1];
    const int*   subjects = (const int*)d_in[2];
    float* out = (float*)d_out;

    char* ws = (char*)d_ws;
    size_t o = 0;
    unsigned short* znbL = (unsigned short*)(ws + o); o += (size_t)MAXPADL * D * 2;  // 2,359,296
    unsigned short* znbS = (unsigned short*)(ws + o); o += (size_t)MAXPADS * D * 2;  // 2,621,440
    float* invn = (float*)(ws + o); o += N * 4;
    int* posL  = (int*)(ws + o); o += N * 4;
    int* posS  = (int*)(ws + o); o += N * 4;
    int* metaL = (int*)(ws + o); o += MAXPADL * 4;
    int* permL = (int*)(ws + o); o += MAXPADL * 4;
    int* metaS = (int*)(ws + o); o += MAXPADS * 4;
    int* permS = (int*)(ws + o); o += MAXPADS * 4;
    int* wvA   = (int*)(ws + o); o += 2048;
    int* wvJ   = (int*)(ws + o); o += 2048;
    int* wvT   = (int*)(ws + o); o += 2048;
    unsigned* posk = (unsigned*)(ws + o); o += N * 4;
    unsigned* negk = (unsigned*)(ws + o); o += N * 4;
    float* per = (float*)(ws + o); o += N * 4;
    float* vld = (float*)(ws + o); o += N * 4;   // total ~5.4 MB

    k_buckets<<<dim3(1), dim3(256), 0, stream>>>(labels, subjects, metaL, permL, posL,
                                                 metaS, permS, posS, wvA, wvJ, wvT);
    k_normalize<<<dim3(N / 4), dim3(256), 0, stream>>>(z, posL, posS, znbL, znbS, invn);
    k_mine<<<dim3(MINEBLOCKS), dim3(256), 0, stream>>>(znbL, znbS, metaL, permL, metaS, permS,
                                                       wvA, wvJ, wvT, posk, negk);
    k_final<<<dim3(N / 4), dim3(256), 0, stream>>>(z, invn, posk, negk, per, vld);
    k_reduce<<<dim3(1), dim3(256), 0, stream>>>(per, vld, out);
}